// Round 1
// baseline (533.491 us; speedup 1.0000x reference)
//
#include <hip/hip_runtime.h>

typedef unsigned short u16;
typedef unsigned int u32;

typedef __bf16 bf16x8 __attribute__((ext_vector_type(8)));
typedef float f32x4 __attribute__((ext_vector_type(4)));
typedef u16 u16x4 __attribute__((ext_vector_type(4)));

__device__ __forceinline__ u16 f2bf(float f) {
  u32 u = __builtin_bit_cast(u32, f);
  u += 0x7fffu + ((u >> 16) & 1u);
  return (u16)(u >> 16);
}

__device__ __forceinline__ void gload_lds16(const void* g, void* lds) {
  __builtin_amdgcn_global_load_lds(
      (const __attribute__((address_space(1))) void*)g,
      (__attribute__((address_space(3))) void*)lds, 16, 0, 0);
}

// ---------------- cast x: fp32 -> bf16 ----------------
__global__ __launch_bounds__(256) void cast_f32_bf16(
    const float* __restrict__ in, u16* __restrict__ out, int n4) {
  int i = (blockIdx.x * 256 + threadIdx.x) * 4;
  float4 v = *reinterpret_cast<const float4*>(in + i);
  u16x4 o;
  o[0] = f2bf(v.x); o[1] = f2bf(v.y); o[2] = f2bf(v.z); o[3] = f2bf(v.w);
  *reinterpret_cast<u16x4*>(out + i) = o;
}

// ---------------- transpose + cast: w[K][N] fp32 -> wt[N][K] bf16 ----------------
__global__ __launch_bounds__(256) void transpose_cast(
    const float* __restrict__ w, u16* __restrict__ wt, int K, int N) {
  __shared__ float tile[32][33];
  int bx = blockIdx.x * 32;  // n
  int by = blockIdx.y * 32;  // k
  int tx = threadIdx.x & 31, ty = threadIdx.x >> 5;
#pragma unroll
  for (int i = 0; i < 32; i += 8)
    tile[ty + i][tx] = w[(size_t)(by + ty + i) * N + bx + tx];
  __syncthreads();
#pragma unroll
  for (int i = 0; i < 32; i += 8)
    wt[(size_t)(bx + ty + i) * K + by + tx] = f2bf(tile[tx][ty + i]);
}

// ---------------- GEMM: C[M][N] = A[M][K](bf16) * BT[N][K](bf16) ----------------
// m97-style: 128x128 tile, BK=32, 4 waves, 4x4 16x16x32 frags/wave.
template <int OUTF32>
__global__ __launch_bounds__(256) void gemm_bt(
    const u16* __restrict__ A, const u16* __restrict__ BT,
    float* __restrict__ Cf, u16* __restrict__ Cb, int M, int N, int K) {
  __shared__ __align__(16) u16 As[128 * 32];
  __shared__ __align__(16) u16 Bs[128 * 32];
  const int t = threadIdx.x;
  const int lane = t & 63;
  const int w = t >> 6;
  const int wr = w >> 1, wc = w & 1;
  const int l15 = lane & 15;
  const int l4 = lane >> 4;
  const int brow = blockIdx.y * 128;
  const int bcol = blockIdx.x * 128;

  f32x4 acc[4][4];
#pragma unroll
  for (int m = 0; m < 4; m++)
#pragma unroll
    for (int n = 0; n < 4; n++)
#pragma unroll
      for (int r = 0; r < 4; r++) acc[m][n][r] = 0.f;

  const size_t Arow0 = (size_t)brow * K;
  const size_t Brow0 = (size_t)bcol * K;

  for (int kk = 0; kk < K; kk += 32) {
#pragma unroll
    for (int c = 0; c < 2; ++c) {
      int chunk = c * 256 + t;
      int row = chunk >> 2;
      int col = (chunk & 3) * 8;
      gload_lds16(&A[Arow0 + (size_t)row * K + kk + col], &As[chunk * 8]);
      gload_lds16(&BT[Brow0 + (size_t)row * K + kk + col], &Bs[chunk * 8]);
    }
    __syncthreads();
    const int k0 = l4 * 8;
    bf16x8 a[4], b[4];
#pragma unroll
    for (int m = 0; m < 4; m++)
      a[m] = *reinterpret_cast<const bf16x8*>(&As[(wr * 64 + m * 16 + l15) * 32 + k0]);
#pragma unroll
    for (int n = 0; n < 4; n++)
      b[n] = *reinterpret_cast<const bf16x8*>(&Bs[(wc * 64 + n * 16 + l15) * 32 + k0]);
#pragma unroll
    for (int m = 0; m < 4; m++)
#pragma unroll
      for (int n = 0; n < 4; n++)
        acc[m][n] = __builtin_amdgcn_mfma_f32_16x16x32_bf16(a[m], b[n], acc[m][n], 0, 0, 0);
    __syncthreads();
  }

#pragma unroll
  for (int m = 0; m < 4; m++) {
    int grow0 = brow + wr * 64 + m * 16 + l4 * 4;
#pragma unroll
    for (int n = 0; n < 4; n++) {
      int gcol = bcol + wc * 64 + n * 16 + l15;
#pragma unroll
      for (int r = 0; r < 4; r++) {
        size_t idx = (size_t)(grow0 + r) * N + gcol;
        if (OUTF32)
          Cf[idx] = acc[m][n][r];
        else
          Cb[idx] = f2bf(acc[m][n][r]);
      }
    }
  }
}

// ---------------- flash attention (causal, GQA) ----------------
// Q [4096][2048] bf16, K/V [4096][512] bf16, out [4096][2048] bf16.
// grid: (T/64, H, B); 4 waves, wave w handles q rows w*16..w*16+15.
__global__ __launch_bounds__(256) void attn_kernel(
    const u16* __restrict__ Qb, const u16* __restrict__ Kb,
    const u16* __restrict__ Vb, u16* __restrict__ Ob) {
  const int qt = blockIdx.x, h = blockIdx.y, b = blockIdx.z;
  const int kvh = h >> 2;
  const int t = threadIdx.x;
  const int lane = t & 63;
  const int w = t >> 6;
  const int l15 = lane & 15, l4 = lane >> 4;

  __shared__ __align__(16) u16 Qs[64 * 64];
  __shared__ __align__(16) u16 Ks[64 * 64];
  __shared__ __align__(16) u16 Vt[64 * 64];  // Vt[d][kv]
  __shared__ __align__(16) u16 Ps[4][16 * 64];

  const int qbase = qt * 64;
  const size_t qrow0 = (size_t)b * 2048 + qbase;

  // load Q tile (async -> first __syncthreads covers it)
#pragma unroll
  for (int c = 0; c < 2; ++c) {
    int chunk = c * 256 + t;
    int row = chunk >> 3, col = (chunk & 7) * 8;
    gload_lds16(&Qb[(qrow0 + row) * 2048 + h * 64 + col], &Qs[chunk * 8]);
  }

  f32x4 o[4];
#pragma unroll
  for (int c = 0; c < 4; c++)
#pragma unroll
    for (int r = 0; r < 4; r++) o[c][r] = 0.f;
  float mrun[4], lrun[4];
#pragma unroll
  for (int r = 0; r < 4; r++) { mrun[r] = -1e30f; lrun[r] = 0.f; }

  const float scale = 0.125f;

  for (int kv = 0; kv <= qt; ++kv) {
    const int kvbase = kv * 64;
    // stage K tile [kv][d]
#pragma unroll
    for (int c = 0; c < 2; ++c) {
      int chunk = c * 256 + t;
      int row = chunk >> 3, col = (chunk & 7) * 8;
      gload_lds16(&Kb[((size_t)b * 2048 + kvbase + row) * 512 + kvh * 64 + col],
                  &Ks[chunk * 8]);
    }
    // stage V transposed: Vt[d][kv]
    {
      int kvr = t & 63, dg = t >> 6;
      const u16* src = &Vb[((size_t)b * 2048 + kvbase + kvr) * 512 + kvh * 64 + dg * 16];
      uint4 v0 = *reinterpret_cast<const uint4*>(src);
      uint4 v1 = *reinterpret_cast<const uint4*>(src + 8);
      __align__(16) u16 tmp[16];
      *reinterpret_cast<uint4*>(&tmp[0]) = v0;
      *reinterpret_cast<uint4*>(&tmp[8]) = v1;
#pragma unroll
      for (int j = 0; j < 16; j++) Vt[(dg * 16 + j) * 64 + kvr] = tmp[j];
    }
    __syncthreads();

    // S = Q K^T  (D rows = q via (l>>4)*4+r, cols = kv via l&15)
    f32x4 s[4];
#pragma unroll
    for (int c = 0; c < 4; c++)
#pragma unroll
      for (int r = 0; r < 4; r++) s[c][r] = 0.f;
#pragma unroll
    for (int ks = 0; ks < 2; ++ks) {
      bf16x8 a = *reinterpret_cast<const bf16x8*>(&Qs[(w * 16 + l15) * 64 + ks * 32 + l4 * 8]);
#pragma unroll
      for (int c = 0; c < 4; c++) {
        bf16x8 bb = *reinterpret_cast<const bf16x8*>(&Ks[(c * 16 + l15) * 64 + ks * 32 + l4 * 8]);
        s[c] = __builtin_amdgcn_mfma_f32_16x16x32_bf16(a, bb, s[c], 0, 0, 0);
      }
    }

    // scale + causal mask
    const int qg = qbase + w * 16 + l4 * 4;
#pragma unroll
    for (int c = 0; c < 4; c++)
#pragma unroll
      for (int r = 0; r < 4; r++) {
        float v = s[c][r] * scale;
        if (kvbase + c * 16 + l15 > qg + r) v = -1e30f;
        s[c][r] = v;
      }

    // online softmax per q row
#pragma unroll
    for (int r = 0; r < 4; r++) {
      float mx = fmaxf(fmaxf(s[0][r], s[1][r]), fmaxf(s[2][r], s[3][r]));
#pragma unroll
      for (int mk = 1; mk < 16; mk <<= 1) mx = fmaxf(mx, __shfl_xor(mx, mk));
      float mnew = fmaxf(mrun[r], mx);
      float alpha = __expf(mrun[r] - mnew);
      mrun[r] = mnew;
      float rs = 0.f;
#pragma unroll
      for (int c = 0; c < 4; c++) {
        float p = __expf(s[c][r] - mnew);
        s[c][r] = p;
        rs += p;
      }
#pragma unroll
      for (int mk = 1; mk < 16; mk <<= 1) rs += __shfl_xor(rs, mk);
      lrun[r] = lrun[r] * alpha + rs;
#pragma unroll
      for (int c = 0; c < 4; c++) o[c][r] *= alpha;
    }

    // write P (bf16) to per-wave LDS
#pragma unroll
    for (int c = 0; c < 4; c++)
#pragma unroll
      for (int r = 0; r < 4; r++)
        Ps[w][(l4 * 4 + r) * 64 + c * 16 + l15] = f2bf(s[c][r]);

    // O += P V  (A = P[q][kv], B = V[kv][d] read from Vt[d][kv])
#pragma unroll
    for (int ks = 0; ks < 2; ++ks) {
      bf16x8 a = *reinterpret_cast<const bf16x8*>(&Ps[w][l15 * 64 + ks * 32 + l4 * 8]);
#pragma unroll
      for (int c = 0; c < 4; c++) {
        bf16x8 bb = *reinterpret_cast<const bf16x8*>(&Vt[(c * 16 + l15) * 64 + ks * 32 + l4 * 8]);
        o[c] = __builtin_amdgcn_mfma_f32_16x16x32_bf16(a, bb, o[c], 0, 0, 0);
      }
    }
    __syncthreads();
  }

  // epilogue: normalize and store
  const size_t orow0 = (size_t)b * 2048 + qbase + w * 16 + l4 * 4;
#pragma unroll
  for (int c = 0; c < 4; c++)
#pragma unroll
    for (int r = 0; r < 4; r++) {
      float val = o[c][r] / lrun[r];
      Ob[(orow0 + r) * 2048 + h * 64 + c * 16 + l15] = f2bf(val);
    }
}

// ---------------- launcher ----------------
extern "C" void kernel_launch(void* const* d_in, const int* in_sizes, int n_in,
                              void* d_out, int out_size, void* d_ws, size_t ws_size,
                              hipStream_t stream) {
  const float* x = (const float*)d_in[0];
  const float* wq = (const float*)d_in[1];
  const float* wk = (const float*)d_in[2];
  const float* wv = (const float*)d_in[3];
  const float* wo = (const float*)d_in[4];
  float* out = (float*)d_out;

  char* p = (char*)d_ws;
  u16* xb = (u16*)p;   p += (size_t)4096 * 2048 * 2;
  u16* wqT = (u16*)p;  p += (size_t)2048 * 2048 * 2;
  u16* wkT = (u16*)p;  p += (size_t)512 * 2048 * 2;
  u16* wvT = (u16*)p;  p += (size_t)512 * 2048 * 2;
  u16* woT = (u16*)p;  p += (size_t)2048 * 2048 * 2;
  u16* Qb = (u16*)p;   p += (size_t)4096 * 2048 * 2;
  u16* Kb = (u16*)p;   p += (size_t)4096 * 512 * 2;
  u16* Vb = (u16*)p;   p += (size_t)4096 * 512 * 2;
  u16* attn = xb;  // reuse: x_bf16 dead after projections

  cast_f32_bf16<<<8192, 256, 0, stream>>>(x, xb, 4096 * 2048);
  transpose_cast<<<dim3(2048 / 32, 2048 / 32), 256, 0, stream>>>(wq, wqT, 2048, 2048);
  transpose_cast<<<dim3(512 / 32, 2048 / 32), 256, 0, stream>>>(wk, wkT, 2048, 512);
  transpose_cast<<<dim3(512 / 32, 2048 / 32), 256, 0, stream>>>(wv, wvT, 2048, 512);
  transpose_cast<<<dim3(2048 / 32, 2048 / 32), 256, 0, stream>>>(wo, woT, 2048, 2048);

  gemm_bt<0><<<dim3(2048 / 128, 4096 / 128), 256, 0, stream>>>(xb, wqT, nullptr, Qb, 4096, 2048, 2048);
  gemm_bt<0><<<dim3(512 / 128, 4096 / 128), 256, 0, stream>>>(xb, wkT, nullptr, Kb, 4096, 512, 2048);
  gemm_bt<0><<<dim3(512 / 128, 4096 / 128), 256, 0, stream>>>(xb, wvT, nullptr, Vb, 4096, 512, 2048);

  attn_kernel<<<dim3(2048 / 64, 32, 2), 256, 0, stream>>>(Qb, Kb, Vb, attn);

  gemm_bt<1><<<dim3(2048 / 128, 4096 / 128), 256, 0, stream>>>(attn, woT, out, nullptr, 4096, 2048, 2048);
}

// Round 2
// 407.982 us; speedup vs baseline: 1.3076x; 1.3076x over previous
//
#include <hip/hip_runtime.h>

typedef unsigned short u16;
typedef unsigned int u32;

typedef __bf16 bf16x8 __attribute__((ext_vector_type(8)));
typedef float f32x4 __attribute__((ext_vector_type(4)));
typedef u16 u16x4 __attribute__((ext_vector_type(4)));

__device__ __forceinline__ u16 f2bf(float f) {
  u32 u = __builtin_bit_cast(u32, f);
  u += 0x7fffu + ((u >> 16) & 1u);
  return (u16)(u >> 16);
}

__device__ __forceinline__ void gload_lds16(const void* g, void* lds) {
  __builtin_amdgcn_global_load_lds(
      (const __attribute__((address_space(1))) void*)g,
      (__attribute__((address_space(3))) void*)lds, 16, 0, 0);
}

// ---------------- cast x: fp32 -> bf16 ----------------
__global__ __launch_bounds__(256) void cast_f32_bf16(
    const float* __restrict__ in, u16* __restrict__ out, int n4) {
  int i = (blockIdx.x * 256 + threadIdx.x) * 4;
  float4 v = *reinterpret_cast<const float4*>(in + i);
  u16x4 o;
  o[0] = f2bf(v.x); o[1] = f2bf(v.y); o[2] = f2bf(v.z); o[3] = f2bf(v.w);
  *reinterpret_cast<u16x4*>(out + i) = o;
}

// ---------------- transpose + cast: w[K][N] fp32 -> wt[N][K] bf16 ----------------
__global__ __launch_bounds__(256) void transpose_cast(
    const float* __restrict__ w, u16* __restrict__ wt, int K, int N) {
  __shared__ float tile[32][33];
  int bx = blockIdx.x * 32;  // n
  int by = blockIdx.y * 32;  // k
  int tx = threadIdx.x & 31, ty = threadIdx.x >> 5;
#pragma unroll
  for (int i = 0; i < 32; i += 8)
    tile[ty + i][tx] = w[(size_t)(by + ty + i) * N + bx + tx];
  __syncthreads();
#pragma unroll
  for (int i = 0; i < 32; i += 8)
    wt[(size_t)(bx + ty + i) * K + by + tx] = f2bf(tile[tx][ty + i]);
}

// ---------------- transpose u16: V[4096][512] -> VT[B*512][2048] ----------------
// VT[(b*512 + col)][t] = V[b*2048 + t][col]
__global__ __launch_bounds__(256) void transpose_u16(
    const u16* __restrict__ in, u16* __restrict__ out) {
  __shared__ u16 tile[32][33];
  int bx = blockIdx.x * 32;  // t dim
  int by = blockIdx.y * 32;  // col dim
  int bz = blockIdx.z;       // batch
  int tx = threadIdx.x & 31, ty = threadIdx.x >> 5;
#pragma unroll
  for (int i = 0; i < 32; i += 8)
    tile[ty + i][tx] = in[((size_t)bz * 2048 + bx + ty + i) * 512 + by + tx];
  __syncthreads();
#pragma unroll
  for (int i = 0; i < 32; i += 8)
    out[((size_t)bz * 512 + by + ty + i) * 2048 + bx + tx] = tile[tx][ty + i];
}

// ---------------- GEMM: C[M][N] = A[M][K](bf16) * BT[N][K](bf16) ----------------
// m97-style: 128x128 tile, BK=32, 4 waves, 4x4 16x16x32 frags/wave.
// MODE 0: bf16 out (Cb, ld=N); MODE 1: f32 out (Cf); MODE 2: split at col 512 -> Cb/Cb2 (ld=512)
template <int MODE>
__global__ __launch_bounds__(256) void gemm_bt(
    const u16* __restrict__ A, const u16* __restrict__ BT,
    float* __restrict__ Cf, u16* __restrict__ Cb, u16* __restrict__ Cb2,
    int M, int N, int K) {
  __shared__ __align__(16) u16 As[128 * 32];
  __shared__ __align__(16) u16 Bs[128 * 32];
  const int t = threadIdx.x;
  const int lane = t & 63;
  const int w = t >> 6;
  const int wr = w >> 1, wc = w & 1;
  const int l15 = lane & 15;
  const int l4 = lane >> 4;
  const int brow = blockIdx.y * 128;
  const int bcol = blockIdx.x * 128;

  f32x4 acc[4][4];
#pragma unroll
  for (int m = 0; m < 4; m++)
#pragma unroll
    for (int n = 0; n < 4; n++)
#pragma unroll
      for (int r = 0; r < 4; r++) acc[m][n][r] = 0.f;

  const size_t Arow0 = (size_t)brow * K;
  const size_t Brow0 = (size_t)bcol * K;

  for (int kk = 0; kk < K; kk += 32) {
#pragma unroll
    for (int c = 0; c < 2; ++c) {
      int chunk = c * 256 + t;
      int row = chunk >> 2;
      int col = (chunk & 3) * 8;
      gload_lds16(&A[Arow0 + (size_t)row * K + kk + col], &As[chunk * 8]);
      gload_lds16(&BT[Brow0 + (size_t)row * K + kk + col], &Bs[chunk * 8]);
    }
    __syncthreads();
    const int k0 = l4 * 8;
    bf16x8 a[4], b[4];
#pragma unroll
    for (int m = 0; m < 4; m++)
      a[m] = *reinterpret_cast<const bf16x8*>(&As[(wr * 64 + m * 16 + l15) * 32 + k0]);
#pragma unroll
    for (int n = 0; n < 4; n++)
      b[n] = *reinterpret_cast<const bf16x8*>(&Bs[(wc * 64 + n * 16 + l15) * 32 + k0]);
#pragma unroll
    for (int m = 0; m < 4; m++)
#pragma unroll
      for (int n = 0; n < 4; n++)
        acc[m][n] = __builtin_amdgcn_mfma_f32_16x16x32_bf16(a[m], b[n], acc[m][n], 0, 0, 0);
    __syncthreads();
  }

#pragma unroll
  for (int m = 0; m < 4; m++) {
    int grow0 = brow + wr * 64 + m * 16 + l4 * 4;
#pragma unroll
    for (int n = 0; n < 4; n++) {
      int gcol = bcol + wc * 64 + n * 16 + l15;
#pragma unroll
      for (int r = 0; r < 4; r++) {
        if (MODE == 1) {
          Cf[(size_t)(grow0 + r) * N + gcol] = acc[m][n][r];
        } else if (MODE == 0) {
          Cb[(size_t)(grow0 + r) * N + gcol] = f2bf(acc[m][n][r]);
        } else {
          if (gcol < 512)
            Cb[(size_t)(grow0 + r) * 512 + gcol] = f2bf(acc[m][n][r]);
          else
            Cb2[(size_t)(grow0 + r) * 512 + gcol - 512] = f2bf(acc[m][n][r]);
        }
      }
    }
  }
}

// ---------------- flash attention (causal, GQA) ----------------
// Q [4096][2048] bf16, K [4096][512] bf16, VT [B*512][2048] bf16, out [4096][2048] bf16.
// grid: (T/64, H, B); 4 waves, wave w handles q rows w*16..w*16+15.
// All LDS tiles XOR-swizzled: u16_idx = row*64 + (col ^ ((row&7)<<3)).
__global__ __launch_bounds__(256) void attn_kernel(
    const u16* __restrict__ Qb, const u16* __restrict__ Kb,
    const u16* __restrict__ VT, u16* __restrict__ Ob) {
  const int qt = blockIdx.x, h = blockIdx.y, b = blockIdx.z;
  const int kvh = h >> 2;
  const int t = threadIdx.x;
  const int lane = t & 63;
  const int w = t >> 6;
  const int l15 = lane & 15, l4 = lane >> 4;

  __shared__ __align__(16) u16 Ks[2][64 * 64];
  __shared__ __align__(16) u16 Vs[2][64 * 64];  // V^T tile: [d][kv]
  __shared__ __align__(16) u16 Ps[4][16 * 64];

  const int qbase = qt * 64;

  // Q fragments in registers: rows qbase + w*16 + l15, cols h*64 + ks*32 + l4*8
  bf16x8 qf[2];
  {
    const size_t qoff =
        ((size_t)b * 2048 + qbase + w * 16 + l15) * 2048 + h * 64 + l4 * 8;
    qf[0] = *reinterpret_cast<const bf16x8*>(&Qb[qoff]);
    qf[1] = *reinterpret_cast<const bf16x8*>(&Qb[qoff + 32]);
  }

  const size_t Krow0 = (size_t)b * 2048;            // + kv row, ld 512
  const size_t Vrow0 = ((size_t)b * 8 + kvh) * 64;  // + d row, ld 2048

  // stage one KV tile (source pre-swizzled so linear LDS == swizzled layout)
  auto stage = [&](int buf, int kvbase) {
#pragma unroll
    for (int c = 0; c < 2; ++c) {
      int chunk = c * 256 + t;
      int row = chunk >> 3, g = chunk & 7;
      int gcs = (g ^ (row & 7)) * 8;
      gload_lds16(&Kb[(Krow0 + kvbase + row) * 512 + kvh * 64 + gcs],
                  &Ks[buf][chunk * 8]);
      gload_lds16(&VT[(Vrow0 + row) * 2048 + kvbase + gcs],
                  &Vs[buf][chunk * 8]);
    }
  };

  f32x4 o[4];
#pragma unroll
  for (int c = 0; c < 4; c++)
#pragma unroll
    for (int r = 0; r < 4; r++) o[c][r] = 0.f;
  float mrun[4], lrun[4];
#pragma unroll
  for (int r = 0; r < 4; r++) { mrun[r] = -1e30f; lrun[r] = 0.f; }

  const float scale = 0.125f;
  const int swzB = (l15 & 7) << 3;  // lane-constant swizzle for frag reads

  stage(0, 0);
  __syncthreads();
  int cur = 0;

  for (int kv = 0; kv <= qt; ++kv) {
    const int kvbase = kv * 64;
    if (kv < qt) stage(cur ^ 1, kvbase + 64);

    // S = Q K^T : D row = q (l4*4+r), col = kv (c*16+l15)
    f32x4 s[4];
#pragma unroll
    for (int c = 0; c < 4; c++)
#pragma unroll
      for (int r = 0; r < 4; r++) s[c][r] = 0.f;
#pragma unroll
    for (int ks = 0; ks < 2; ++ks) {
      const int kcol = (ks * 32 + l4 * 8) ^ swzB;
#pragma unroll
      for (int c = 0; c < 4; c++) {
        bf16x8 kb = *reinterpret_cast<const bf16x8*>(
            &Ks[cur][(c * 16 + l15) * 64 + kcol]);
        s[c] = __builtin_amdgcn_mfma_f32_16x16x32_bf16(qf[ks], kb, s[c], 0, 0, 0);
      }
    }

    // scale + causal mask
    const int qg = qbase + w * 16 + l4 * 4;
#pragma unroll
    for (int c = 0; c < 4; c++)
#pragma unroll
      for (int r = 0; r < 4; r++) {
        float v = s[c][r] * scale;
        if (kvbase + c * 16 + l15 > qg + r) v = -1e30f;
        s[c][r] = v;
      }

    // online softmax per q row (16-lane butterfly over l15)
#pragma unroll
    for (int r = 0; r < 4; r++) {
      float mx = fmaxf(fmaxf(s[0][r], s[1][r]), fmaxf(s[2][r], s[3][r]));
#pragma unroll
      for (int mk = 1; mk < 16; mk <<= 1) mx = fmaxf(mx, __shfl_xor(mx, mk));
      float mnew = fmaxf(mrun[r], mx);
      float alpha = __expf(mrun[r] - mnew);
      mrun[r] = mnew;
      float rs = 0.f;
#pragma unroll
      for (int c = 0; c < 4; c++) {
        float p = __expf(s[c][r] - mnew);
        s[c][r] = p;
        rs += p;
      }
#pragma unroll
      for (int mk = 1; mk < 16; mk <<= 1) rs += __shfl_xor(rs, mk);
      lrun[r] = lrun[r] * alpha + rs;
#pragma unroll
      for (int c = 0; c < 4; c++) o[c][r] *= alpha;
    }

    // write P (bf16) to per-wave LDS, swizzled
#pragma unroll
    for (int c = 0; c < 4; c++)
#pragma unroll
      for (int r = 0; r < 4; r++) {
        int prow = l4 * 4 + r;
        Ps[w][prow * 64 + ((c * 16 + l15) ^ ((prow & 7) << 3))] = f2bf(s[c][r]);
      }

    // O += P V : A = P[q][kv] (row=l15), B = V^T[d][kv] (row=c*16+l15)
#pragma unroll
    for (int ks = 0; ks < 2; ++ks) {
      const int pcol = (ks * 32 + l4 * 8) ^ swzB;
      bf16x8 a = *reinterpret_cast<const bf16x8*>(&Ps[w][l15 * 64 + pcol]);
#pragma unroll
      for (int c = 0; c < 4; c++) {
        bf16x8 bb = *reinterpret_cast<const bf16x8*>(
            &Vs[cur][(c * 16 + l15) * 64 + pcol]);
        o[c] = __builtin_amdgcn_mfma_f32_16x16x32_bf16(a, bb, o[c], 0, 0, 0);
      }
    }

    __syncthreads();
    cur ^= 1;
  }

  // epilogue: normalize and store
  const size_t orow0 = (size_t)b * 2048 + qbase + w * 16 + l4 * 4;
#pragma unroll
  for (int c = 0; c < 4; c++)
#pragma unroll
    for (int r = 0; r < 4; r++) {
      float val = o[c][r] / lrun[r];
      Ob[(orow0 + r) * 2048 + h * 64 + c * 16 + l15] = f2bf(val);
    }
}

// ---------------- launcher ----------------
extern "C" void kernel_launch(void* const* d_in, const int* in_sizes, int n_in,
                              void* d_out, int out_size, void* d_ws, size_t ws_size,
                              hipStream_t stream) {
  const float* x = (const float*)d_in[0];
  const float* wq = (const float*)d_in[1];
  const float* wk = (const float*)d_in[2];
  const float* wv = (const float*)d_in[3];
  const float* wo = (const float*)d_in[4];
  float* out = (float*)d_out;

  char* p = (char*)d_ws;
  u16* xb = (u16*)p;   p += (size_t)4096 * 2048 * 2;
  u16* wqT = (u16*)p;  p += (size_t)2048 * 2048 * 2;
  u16* wkT = (u16*)p;  p += (size_t)512 * 2048 * 2;   // contiguous with wvT:
  u16* wvT = (u16*)p;  p += (size_t)512 * 2048 * 2;   //   fused KV GEMM uses wkT base, N=1024
  u16* woT = (u16*)p;  p += (size_t)2048 * 2048 * 2;
  u16* Qb = (u16*)p;   p += (size_t)4096 * 2048 * 2;
  u16* Kb = (u16*)p;   p += (size_t)4096 * 512 * 2;
  u16* Vb = (u16*)p;   p += (size_t)4096 * 512 * 2;
  u16* VTb = (u16*)p;  p += (size_t)2 * 512 * 2048 * 2;
  u16* attn = xb;  // reuse: x_bf16 dead after projections

  cast_f32_bf16<<<8192, 256, 0, stream>>>(x, xb, 4096 * 2048);
  transpose_cast<<<dim3(2048 / 32, 2048 / 32), 256, 0, stream>>>(wq, wqT, 2048, 2048);
  transpose_cast<<<dim3(512 / 32, 2048 / 32), 256, 0, stream>>>(wk, wkT, 2048, 512);
  transpose_cast<<<dim3(512 / 32, 2048 / 32), 256, 0, stream>>>(wv, wvT, 2048, 512);
  transpose_cast<<<dim3(2048 / 32, 2048 / 32), 256, 0, stream>>>(wo, woT, 2048, 2048);

  gemm_bt<0><<<dim3(2048 / 128, 4096 / 128), 256, 0, stream>>>(
      xb, wqT, nullptr, Qb, nullptr, 4096, 2048, 2048);
  gemm_bt<2><<<dim3(1024 / 128, 4096 / 128), 256, 0, stream>>>(
      xb, wkT, nullptr, Kb, Vb, 4096, 1024, 2048);

  transpose_u16<<<dim3(2048 / 32, 512 / 32, 2), 256, 0, stream>>>(Vb, VTb);

  attn_kernel<<<dim3(2048 / 64, 32, 2), 256, 0, stream>>>(Qb, Kb, VTb, attn);

  gemm_bt<1><<<dim3(2048 / 128, 4096 / 128), 256, 0, stream>>>(
      attn, woT, out, nullptr, nullptr, 4096, 2048, 2048);
}

// Round 3
// 313.368 us; speedup vs baseline: 1.7024x; 1.3019x over previous
//
#include <hip/hip_runtime.h>

typedef unsigned short u16;
typedef unsigned int u32;
typedef unsigned long long u64;

typedef __bf16 bf16x8 __attribute__((ext_vector_type(8)));
typedef float f32x4 __attribute__((ext_vector_type(4)));
typedef u16 u16x4 __attribute__((ext_vector_type(4)));

__device__ __forceinline__ u16 f2bf(float f) {
  u32 u = __builtin_bit_cast(u32, f);
  u += 0x7fffu + ((u >> 16) & 1u);
  return (u16)(u >> 16);
}

__device__ __forceinline__ u32 packbf2(float a, float b) {
  __bf16 x = (__bf16)a, y = (__bf16)b;
  return (u32)__builtin_bit_cast(u16, x) | ((u32)__builtin_bit_cast(u16, y) << 16);
}

__device__ __forceinline__ float fexp2(float x) {
#if __has_builtin(__builtin_amdgcn_exp2f)
  return __builtin_amdgcn_exp2f(x);
#else
  return exp2f(x);
#endif
}

__device__ __forceinline__ void gload_lds16(const void* g, void* lds) {
  __builtin_amdgcn_global_load_lds(
      (const __attribute__((address_space(1))) void*)g,
      (__attribute__((address_space(3))) void*)lds, 16, 0, 0);
}

// 0.125 (1/sqrt(64)) * log2(e) — folded into Q projection so softmax runs in exp2 domain
#define QSCALE 0.18033688011112043f

// ---------------- cast x: fp32 -> bf16 ----------------
__global__ __launch_bounds__(256) void cast_f32_bf16(
    const float* __restrict__ in, u16* __restrict__ out, int n4) {
  int i = (blockIdx.x * 256 + threadIdx.x) * 4;
  float4 v = *reinterpret_cast<const float4*>(in + i);
  u16x4 o;
  o[0] = f2bf(v.x); o[1] = f2bf(v.y); o[2] = f2bf(v.z); o[3] = f2bf(v.w);
  *reinterpret_cast<u16x4*>(out + i) = o;
}

// ---------------- transpose + cast: w[K][N] fp32 -> wt[N][K] bf16 ----------------
__global__ __launch_bounds__(256) void transpose_cast(
    const float* __restrict__ w, u16* __restrict__ wt, int K, int N) {
  __shared__ float tile[32][33];
  int bx = blockIdx.x * 32;  // n
  int by = blockIdx.y * 32;  // k
  int tx = threadIdx.x & 31, ty = threadIdx.x >> 5;
#pragma unroll
  for (int i = 0; i < 32; i += 8)
    tile[ty + i][tx] = w[(size_t)(by + ty + i) * N + bx + tx];
  __syncthreads();
#pragma unroll
  for (int i = 0; i < 32; i += 8)
    wt[(size_t)(bx + ty + i) * K + by + tx] = f2bf(tile[tx][ty + i]);
}

// ---------------- transpose u16: V[4096][512] -> VT[B*512][2048] ----------------
__global__ __launch_bounds__(256) void transpose_u16(
    const u16* __restrict__ in, u16* __restrict__ out) {
  __shared__ u16 tile[32][33];
  int bx = blockIdx.x * 32;  // t dim
  int by = blockIdx.y * 32;  // col dim
  int bz = blockIdx.z;       // batch
  int tx = threadIdx.x & 31, ty = threadIdx.x >> 5;
#pragma unroll
  for (int i = 0; i < 32; i += 8)
    tile[ty + i][tx] = in[((size_t)bz * 2048 + bx + ty + i) * 512 + by + tx];
  __syncthreads();
#pragma unroll
  for (int i = 0; i < 32; i += 8)
    out[((size_t)bz * 512 + by + ty + i) * 2048 + bx + tx] = tile[tx][ty + i];
}

// ---------------- GEMM: C[M][N] = A[M][K](bf16) * BT[N][K](bf16) ----------------
// MODE 0: bf16 out scaled by oscale; MODE 1: f32 out; MODE 2: split at col 512 -> Cb/Cb2
template <int MODE>
__global__ __launch_bounds__(256) void gemm_bt(
    const u16* __restrict__ A, const u16* __restrict__ BT,
    float* __restrict__ Cf, u16* __restrict__ Cb, u16* __restrict__ Cb2,
    int M, int N, int K, float oscale) {
  __shared__ __align__(16) u16 As[128 * 32];
  __shared__ __align__(16) u16 Bs[128 * 32];
  const int t = threadIdx.x;
  const int lane = t & 63;
  const int w = t >> 6;
  const int wr = w >> 1, wc = w & 1;
  const int l15 = lane & 15;
  const int l4 = lane >> 4;
  const int brow = blockIdx.y * 128;
  const int bcol = blockIdx.x * 128;

  f32x4 acc[4][4];
#pragma unroll
  for (int m = 0; m < 4; m++)
#pragma unroll
    for (int n = 0; n < 4; n++)
#pragma unroll
      for (int r = 0; r < 4; r++) acc[m][n][r] = 0.f;

  const size_t Arow0 = (size_t)brow * K;
  const size_t Brow0 = (size_t)bcol * K;

  for (int kk = 0; kk < K; kk += 32) {
#pragma unroll
    for (int c = 0; c < 2; ++c) {
      int chunk = c * 256 + t;
      int row = chunk >> 2;
      int col = (chunk & 3) * 8;
      gload_lds16(&A[Arow0 + (size_t)row * K + kk + col], &As[chunk * 8]);
      gload_lds16(&BT[Brow0 + (size_t)row * K + kk + col], &Bs[chunk * 8]);
    }
    __syncthreads();
    const int k0 = l4 * 8;
    bf16x8 a[4], b[4];
#pragma unroll
    for (int m = 0; m < 4; m++)
      a[m] = *reinterpret_cast<const bf16x8*>(&As[(wr * 64 + m * 16 + l15) * 32 + k0]);
#pragma unroll
    for (int n = 0; n < 4; n++)
      b[n] = *reinterpret_cast<const bf16x8*>(&Bs[(wc * 64 + n * 16 + l15) * 32 + k0]);
#pragma unroll
    for (int m = 0; m < 4; m++)
#pragma unroll
      for (int n = 0; n < 4; n++)
        acc[m][n] = __builtin_amdgcn_mfma_f32_16x16x32_bf16(a[m], b[n], acc[m][n], 0, 0, 0);
    __syncthreads();
  }

#pragma unroll
  for (int m = 0; m < 4; m++) {
    int grow0 = brow + wr * 64 + m * 16 + l4 * 4;
#pragma unroll
    for (int n = 0; n < 4; n++) {
      int gcol = bcol + wc * 64 + n * 16 + l15;
#pragma unroll
      for (int r = 0; r < 4; r++) {
        if (MODE == 1) {
          Cf[(size_t)(grow0 + r) * N + gcol] = acc[m][n][r];
        } else if (MODE == 0) {
          Cb[(size_t)(grow0 + r) * N + gcol] = f2bf(acc[m][n][r] * oscale);
        } else {
          if (gcol < 512)
            Cb[(size_t)(grow0 + r) * 512 + gcol] = f2bf(acc[m][n][r]);
          else
            Cb2[(size_t)(grow0 + r) * 512 + gcol - 512] = f2bf(acc[m][n][r]);
        }
      }
    }
  }
}

// ---------------- flash attention v3 (causal, GQA, swapped QK^T) ----------------
// Q [4096][2048] bf16 (pre-scaled by QSCALE), K [4096][512] bf16,
// VT [B*512][2048] bf16, out [4096][2048] bf16.
// grid: (16, 32, 2); 4 waves; wave w owns q rows [qt*128 + w*32, +32) (2 subtiles of 16).
// Swapped mfma(K,Q): lane (g=l>>4, q=l&15) holds S^T[kv = c*16+g*4+r][q].
__global__ __launch_bounds__(256, 2) void attn_kernel(
    const u16* __restrict__ Qb, const u16* __restrict__ Kb,
    const u16* __restrict__ VT, u16* __restrict__ Ob) {
  const int qt = (int)gridDim.x - 1 - blockIdx.x;  // descending: long blocks first
  const int h = blockIdx.y, b = blockIdx.z;
  const int kvh = h >> 2;
  const int t = threadIdx.x;
  const int lane = t & 63;
  const int w = t >> 6;
  const int q15 = lane & 15, g = lane >> 4;

  __shared__ __align__(16) u16 Ks[2][64 * 64];
  __shared__ __align__(16) u16 Vs[2][64 * 64];  // V^T tile: [d][kv]
  __shared__ __align__(16) u32 Pu[4][16 * 32];  // per-wave P / epilogue buffer

  const int qbase = qt * 128;
  const int wq0 = qbase + w * 32;

  // Q fragments: qf[sub][ks] — B-operand layout (row=q15, k-chunk=g*8)
  bf16x8 qf[2][2];
  {
    const u16* q0 = &Qb[((size_t)b * 2048 + wq0 + q15) * 2048 + h * 64 + g * 8];
    qf[0][0] = *reinterpret_cast<const bf16x8*>(q0);
    qf[0][1] = *reinterpret_cast<const bf16x8*>(q0 + 32);
    qf[1][0] = *reinterpret_cast<const bf16x8*>(q0 + 16 * 2048);
    qf[1][1] = *reinterpret_cast<const bf16x8*>(q0 + 16 * 2048 + 32);
  }

  const size_t Krow0 = (size_t)b * 2048;
  const size_t Vrow0 = ((size_t)b * 8 + kvh) * 64;

  auto stage = [&](int buf, int kvbase) {
#pragma unroll
    for (int c = 0; c < 2; ++c) {
      int chunk = c * 256 + t;
      int row = chunk >> 3, gg = chunk & 7;
      int gcs = (gg ^ (row & 7)) * 8;
      gload_lds16(&Kb[(Krow0 + kvbase + row) * 512 + kvh * 64 + gcs],
                  &Ks[buf][chunk * 8]);
      gload_lds16(&VT[(Vrow0 + row) * 2048 + kvbase + gcs],
                  &Vs[buf][chunk * 8]);
    }
  };

  f32x4 oo[2][4];  // O^T accum: oo[sub][c2], d = c2*16+g*4+r, col q=q15
#pragma unroll
  for (int s2 = 0; s2 < 2; s2++)
#pragma unroll
    for (int c = 0; c < 4; c++)
#pragma unroll
      for (int r = 0; r < 4; r++) oo[s2][c][r] = 0.f;
  float mr[2] = {-1e30f, -1e30f}, lr[2] = {0.f, 0.f};

  const int swzB = (q15 & 7) << 3;  // u16-unit frag-read swizzle (matches stage)
  const int swzP = (q15 & 7) << 2;  // u32-unit swizzle for Pu
  const int ktiles = 2 * qt + 2;
  const int mylast = (wq0 + 31) >> 6;  // wave's last causal tile
  u32* const pw = &Pu[w][0];

  stage(0, 0);
  __syncthreads();
  int cur = 0;

  for (int kv = 0; kv < ktiles; ++kv) {
    const int kvbase = kv << 6;
    if (kv + 1 < ktiles) stage(cur ^ 1, kvbase + 64);

    if (kv <= mylast) {
      // ---- S^T = K Q^T : D[kv][q] ----
      f32x4 s[2][4];
#pragma unroll
      for (int s2 = 0; s2 < 2; s2++)
#pragma unroll
        for (int c = 0; c < 4; c++)
#pragma unroll
          for (int r = 0; r < 4; r++) s[s2][c][r] = 0.f;
      __builtin_amdgcn_s_setprio(1);
#pragma unroll
      for (int ks = 0; ks < 2; ++ks) {
        const int kcol = (ks * 32 + g * 8) ^ swzB;
#pragma unroll
        for (int c = 0; c < 4; c++) {
          bf16x8 kb = *reinterpret_cast<const bf16x8*>(
              &Ks[cur][(c * 16 + q15) * 64 + kcol]);
          s[0][c] = __builtin_amdgcn_mfma_f32_16x16x32_bf16(kb, qf[0][ks], s[0][c], 0, 0, 0);
          s[1][c] = __builtin_amdgcn_mfma_f32_16x16x32_bf16(kb, qf[1][ks], s[1][c], 0, 0, 0);
        }
      }
      __builtin_amdgcn_s_setprio(0);

      bf16x8 pb[2][2];
#pragma unroll
      for (int sub = 0; sub < 2; ++sub) {
        const int qg = wq0 + sub * 16 + q15;
        // causal mask (diagonal tiles only; wave-uniform branch)
        if (kvbase + 63 > wq0 + sub * 16) {
#pragma unroll
          for (int c = 0; c < 4; c++)
#pragma unroll
            for (int r = 0; r < 4; r++)
              if (kvbase + c * 16 + g * 4 + r > qg) s[sub][c][r] = -1e30f;
        }
        // in-lane max over 16, then cross-g reduce (2 shfl)
        float mx0 = fmaxf(fmaxf(s[sub][0][0], s[sub][0][1]), fmaxf(s[sub][0][2], s[sub][0][3]));
        float mx1 = fmaxf(fmaxf(s[sub][1][0], s[sub][1][1]), fmaxf(s[sub][1][2], s[sub][1][3]));
        float mx2 = fmaxf(fmaxf(s[sub][2][0], s[sub][2][1]), fmaxf(s[sub][2][2], s[sub][2][3]));
        float mx3 = fmaxf(fmaxf(s[sub][3][0], s[sub][3][1]), fmaxf(s[sub][3][2], s[sub][3][3]));
        float mx = fmaxf(fmaxf(mx0, mx1), fmaxf(mx2, mx3));
        mx = fmaxf(mx, __shfl_xor(mx, 16));
        mx = fmaxf(mx, __shfl_xor(mx, 32));
        float mnew = fmaxf(mr[sub], mx);
        float alpha = fexp2(mr[sub] - mnew);
        mr[sub] = mnew;
        float p[4][4];
        float rs = 0.f;
#pragma unroll
        for (int c = 0; c < 4; c++) {
          float t0 = fexp2(s[sub][c][0] - mnew);
          float t1 = fexp2(s[sub][c][1] - mnew);
          float t2 = fexp2(s[sub][c][2] - mnew);
          float t3 = fexp2(s[sub][c][3] - mnew);
          p[c][0] = t0; p[c][1] = t1; p[c][2] = t2; p[c][3] = t3;
          rs += (t0 + t1) + (t2 + t3);
        }
        rs += __shfl_xor(rs, 16);
        rs += __shfl_xor(rs, 32);
        lr[sub] = lr[sub] * alpha + rs;
#pragma unroll
        for (int c = 0; c < 4; c++)
#pragma unroll
          for (int r = 0; r < 4; r++) oo[sub][c][r] *= alpha;
        // pack P -> per-wave LDS (b64 writes, K-style swizzle)
#pragma unroll
        for (int c = 0; c < 4; c++) {
          u64 wv = (u64)packbf2(p[c][0], p[c][1]) |
                   ((u64)packbf2(p[c][2], p[c][3]) << 32);
          *reinterpret_cast<u64*>(&pw[q15 * 32 + ((c * 8 + g * 2) ^ swzP)]) = wv;
        }
        // read back as B-fragment (row=q15, kv-chunk=g*8)
#pragma unroll
        for (int ks = 0; ks < 2; ++ks)
          pb[sub][ks] = *reinterpret_cast<const bf16x8*>(
              &pw[q15 * 32 + ((ks * 16 + g * 4) ^ swzP)]);
      }

      // ---- O^T += V^T P : D[d][q] ----
      __builtin_amdgcn_s_setprio(1);
#pragma unroll
      for (int ks = 0; ks < 2; ++ks) {
        const int vcol = (ks * 32 + g * 8) ^ swzB;
#pragma unroll
        for (int c2 = 0; c2 < 4; c2++) {
          bf16x8 vb = *reinterpret_cast<const bf16x8*>(
              &Vs[cur][(c2 * 16 + q15) * 64 + vcol]);
          oo[0][c2] = __builtin_amdgcn_mfma_f32_16x16x32_bf16(vb, pb[0][ks], oo[0][c2], 0, 0, 0);
          oo[1][c2] = __builtin_amdgcn_mfma_f32_16x16x32_bf16(vb, pb[1][ks], oo[1][c2], 0, 0, 0);
        }
      }
      __builtin_amdgcn_s_setprio(0);
    }

    __syncthreads();
    cur ^= 1;
  }

  // ---- epilogue: normalize, transpose via LDS, coalesced store ----
  const int qq = lane >> 2, cl = lane & 3;
  const int swq = (qq & 7) << 2;
#pragma unroll
  for (int sub = 0; sub < 2; ++sub) {
    float rcp = 1.0f / lr[sub];
#pragma unroll
    for (int c2 = 0; c2 < 4; c2++) {
      u64 wv = (u64)packbf2(oo[sub][c2][0] * rcp, oo[sub][c2][1] * rcp) |
               ((u64)packbf2(oo[sub][c2][2] * rcp, oo[sub][c2][3] * rcp) << 32);
      *reinterpret_cast<u64*>(&pw[q15 * 32 + ((c2 * 8 + g * 2) ^ swzP)]) = wv;
    }
    uint4 d0 = *reinterpret_cast<const uint4*>(&pw[qq * 32 + ((cl * 4) ^ swq)]);
    uint4 d1 = *reinterpret_cast<const uint4*>(&pw[qq * 32 + ((cl * 4 + 16) ^ swq)]);
    u32* og = (u32*)Ob + ((size_t)b * 2048 + qbase + w * 32 + sub * 16 + qq) * 1024 + h * 32;
    *reinterpret_cast<uint4*>(&og[cl * 4]) = d0;
    *reinterpret_cast<uint4*>(&og[cl * 4 + 16]) = d1;
  }
}

// ---------------- launcher ----------------
extern "C" void kernel_launch(void* const* d_in, const int* in_sizes, int n_in,
                              void* d_out, int out_size, void* d_ws, size_t ws_size,
                              hipStream_t stream) {
  const float* x = (const float*)d_in[0];
  const float* wq = (const float*)d_in[1];
  const float* wk = (const float*)d_in[2];
  const float* wv = (const float*)d_in[3];
  const float* wo = (const float*)d_in[4];
  float* out = (float*)d_out;

  char* p = (char*)d_ws;
  u16* xb = (u16*)p;   p += (size_t)4096 * 2048 * 2;
  u16* wqT = (u16*)p;  p += (size_t)2048 * 2048 * 2;
  u16* wkT = (u16*)p;  p += (size_t)512 * 2048 * 2;   // contiguous with wvT (fused KV GEMM)
  u16* wvT = (u16*)p;  p += (size_t)512 * 2048 * 2;
  u16* woT = (u16*)p;  p += (size_t)2048 * 2048 * 2;
  u16* Qb = (u16*)p;   p += (size_t)4096 * 2048 * 2;
  u16* Kb = (u16*)p;   p += (size_t)4096 * 512 * 2;
  u16* Vb = (u16*)p;   p += (size_t)4096 * 512 * 2;
  u16* VTb = (u16*)p;  p += (size_t)2 * 512 * 2048 * 2;
  u16* attn = xb;  // reuse: x_bf16 dead after projections

  cast_f32_bf16<<<8192, 256, 0, stream>>>(x, xb, 4096 * 2048);
  transpose_cast<<<dim3(2048 / 32, 2048 / 32), 256, 0, stream>>>(wq, wqT, 2048, 2048);
  transpose_cast<<<dim3(512 / 32, 2048 / 32), 256, 0, stream>>>(wk, wkT, 2048, 512);
  transpose_cast<<<dim3(512 / 32, 2048 / 32), 256, 0, stream>>>(wv, wvT, 2048, 512);
  transpose_cast<<<dim3(2048 / 32, 2048 / 32), 256, 0, stream>>>(wo, woT, 2048, 2048);

  // Q projection pre-scaled by 1/sqrt(dh)*log2(e) for exp2-domain softmax
  gemm_bt<0><<<dim3(2048 / 128, 4096 / 128), 256, 0, stream>>>(
      xb, wqT, nullptr, Qb, nullptr, 4096, 2048, 2048, QSCALE);
  gemm_bt<2><<<dim3(1024 / 128, 4096 / 128), 256, 0, stream>>>(
      xb, wkT, nullptr, Kb, Vb, 4096, 1024, 2048, 1.0f);

  transpose_u16<<<dim3(2048 / 32, 512 / 32, 2), 256, 0, stream>>>(Vb, VTb);

  attn_kernel<<<dim3(2048 / 128, 32, 2), 256, 0, stream>>>(Qb, Kb, VTb, attn);

  gemm_bt<1><<<dim3(2048 / 128, 4096 / 128), 256, 0, stream>>>(
      attn, woT, out, nullptr, nullptr, 4096, 2048, 2048, 1.0f);
}

// Round 4
// 237.307 us; speedup vs baseline: 2.2481x; 1.3205x over previous
//
#include <hip/hip_runtime.h>

typedef unsigned short u16;
typedef unsigned int u32;
typedef unsigned long long u64;

typedef __bf16 bf16x8 __attribute__((ext_vector_type(8)));
typedef float f32x4 __attribute__((ext_vector_type(4)));
typedef u16 u16x4 __attribute__((ext_vector_type(4)));

__device__ __forceinline__ u16 f2bf(float f) {
  u32 u = __builtin_bit_cast(u32, f);
  u += 0x7fffu + ((u >> 16) & 1u);
  return (u16)(u >> 16);
}

__device__ __forceinline__ u32 packbf2(float a, float b) {
  __bf16 x = (__bf16)a, y = (__bf16)b;
  return (u32)__builtin_bit_cast(u16, x) | ((u32)__builtin_bit_cast(u16, y) << 16);
}

__device__ __forceinline__ float fexp2(float x) {
#if __has_builtin(__builtin_amdgcn_exp2f)
  return __builtin_amdgcn_exp2f(x);
#else
  return exp2f(x);
#endif
}

__device__ __forceinline__ void gload_lds16(const void* g, void* lds) {
  __builtin_amdgcn_global_load_lds(
      (const __attribute__((address_space(1))) void*)g,
      (__attribute__((address_space(3))) void*)lds, 16, 0, 0);
}

// 0.125 (1/sqrt(64)) * log2(e) — folded into Q projection so softmax runs in exp2 domain
#define QSCALE 0.18033688011112043f

// ---------------- cast x: fp32 -> bf16 ----------------
__global__ __launch_bounds__(256) void cast_f32_bf16(
    const float* __restrict__ in, u16* __restrict__ out, int n4) {
  int i = (blockIdx.x * 256 + threadIdx.x) * 4;
  float4 v = *reinterpret_cast<const float4*>(in + i);
  u16x4 o;
  o[0] = f2bf(v.x); o[1] = f2bf(v.y); o[2] = f2bf(v.z); o[3] = f2bf(v.w);
  *reinterpret_cast<u16x4*>(out + i) = o;
}

// ---------------- transpose + cast: w[K][N] fp32 -> wt[N][K] bf16 ----------------
__global__ __launch_bounds__(256) void transpose_cast(
    const float* __restrict__ w, u16* __restrict__ wt, int K, int N) {
  __shared__ float tile[32][33];
  int bx = blockIdx.x * 32;  // n
  int by = blockIdx.y * 32;  // k
  int tx = threadIdx.x & 31, ty = threadIdx.x >> 5;
#pragma unroll
  for (int i = 0; i < 32; i += 8)
    tile[ty + i][tx] = w[(size_t)(by + ty + i) * N + bx + tx];
  __syncthreads();
#pragma unroll
  for (int i = 0; i < 32; i += 8)
    wt[(size_t)(bx + ty + i) * K + by + tx] = f2bf(tile[tx][ty + i]);
}

// ---------------- transpose u16: V[4096][512] -> VT[B*512][2048] ----------------
__global__ __launch_bounds__(256) void transpose_u16(
    const u16* __restrict__ in, u16* __restrict__ out) {
  __shared__ u16 tile[32][33];
  int bx = blockIdx.x * 32;  // t dim
  int by = blockIdx.y * 32;  // col dim
  int bz = blockIdx.z;       // batch
  int tx = threadIdx.x & 31, ty = threadIdx.x >> 5;
#pragma unroll
  for (int i = 0; i < 32; i += 8)
    tile[ty + i][tx] = in[((size_t)bz * 2048 + bx + ty + i) * 512 + by + tx];
  __syncthreads();
#pragma unroll
  for (int i = 0; i < 32; i += 8)
    out[((size_t)bz * 512 + by + ty + i) * 2048 + bx + tx] = tile[tx][ty + i];
}

// ---------------- GEMM: C[M][N] = A[M][K](bf16) * BT[N][K](bf16) ----------------
// MODE 1: f32 out (ld=N). MODE 3: fused QKV split — cols [0,2048) -> Cb (Q, ld2048,
// scaled by QSCALE), [2048,2560) -> Cb2 (K, ld512), [2560,3072) -> Cb3 (V, ld512).
// XCD-aware bijective block swizzle (requires nwg % 8 == 0).
template <int MODE>
__global__ __launch_bounds__(256) void gemm_bt(
    const u16* __restrict__ A, const u16* __restrict__ BT,
    float* __restrict__ Cf, u16* __restrict__ Cb, u16* __restrict__ Cb2,
    u16* __restrict__ Cb3, int M, int N, int K) {
  __shared__ __align__(16) u16 As[128 * 32];
  __shared__ __align__(16) u16 Bs[128 * 32];
  const int t = threadIdx.x;
  const int lane = t & 63;
  const int w = t >> 6;
  const int wr = w >> 1, wc = w & 1;
  const int l15 = lane & 15;
  const int l4 = lane >> 4;

  // XCD swizzle: each XCD gets a contiguous chunk of the row-major tile space
  const int nwg = gridDim.x * gridDim.y;
  const int bid = blockIdx.y * gridDim.x + blockIdx.x;
  const int wg = (bid & 7) * (nwg >> 3) + (bid >> 3);
  const int brow = (wg / gridDim.x) * 128;
  const int bcol = (wg % gridDim.x) * 128;

  f32x4 acc[4][4];
#pragma unroll
  for (int m = 0; m < 4; m++)
#pragma unroll
    for (int n = 0; n < 4; n++)
#pragma unroll
      for (int r = 0; r < 4; r++) acc[m][n][r] = 0.f;

  const size_t Arow0 = (size_t)brow * K;
  const size_t Brow0 = (size_t)bcol * K;

  for (int kk = 0; kk < K; kk += 32) {
#pragma unroll
    for (int c = 0; c < 2; ++c) {
      int chunk = c * 256 + t;
      int row = chunk >> 2;
      int col = (chunk & 3) * 8;
      gload_lds16(&A[Arow0 + (size_t)row * K + kk + col], &As[chunk * 8]);
      gload_lds16(&BT[Brow0 + (size_t)row * K + kk + col], &Bs[chunk * 8]);
    }
    __syncthreads();
    const int k0 = l4 * 8;
    bf16x8 a[4], b[4];
#pragma unroll
    for (int m = 0; m < 4; m++)
      a[m] = *reinterpret_cast<const bf16x8*>(&As[(wr * 64 + m * 16 + l15) * 32 + k0]);
#pragma unroll
    for (int n = 0; n < 4; n++)
      b[n] = *reinterpret_cast<const bf16x8*>(&Bs[(wc * 64 + n * 16 + l15) * 32 + k0]);
#pragma unroll
    for (int m = 0; m < 4; m++)
#pragma unroll
      for (int n = 0; n < 4; n++)
        acc[m][n] = __builtin_amdgcn_mfma_f32_16x16x32_bf16(a[m], b[n], acc[m][n], 0, 0, 0);
    __syncthreads();
  }

#pragma unroll
  for (int m = 0; m < 4; m++) {
    int grow0 = brow + wr * 64 + m * 16 + l4 * 4;
#pragma unroll
    for (int n = 0; n < 4; n++) {
      int gcol = bcol + wc * 64 + n * 16 + l15;
#pragma unroll
      for (int r = 0; r < 4; r++) {
        if (MODE == 1) {
          Cf[(size_t)(grow0 + r) * N + gcol] = acc[m][n][r];
        } else {  // MODE 3 — bcol is 128-aligned so whole block is in one region
          if (bcol < 2048)
            Cb[(size_t)(grow0 + r) * 2048 + gcol] = f2bf(acc[m][n][r] * QSCALE);
          else if (bcol < 2560)
            Cb2[(size_t)(grow0 + r) * 512 + (gcol - 2048)] = f2bf(acc[m][n][r]);
          else
            Cb3[(size_t)(grow0 + r) * 512 + (gcol - 2560)] = f2bf(acc[m][n][r]);
        }
      }
    }
  }
}

// ---------------- flash attention v4 (causal, GQA, swapped QK^T, paired q-tiles) --
// Q [4096][2048] bf16 (pre-scaled), K [4096][512] bf16, VT [B*512][2048] bf16,
// out [4096][2048] bf16.
// grid: (8, 32, 2). Block jj processes q-tile (15-jj) then q-tile jj (128 rows each)
// -> every block does exactly 34 kv-tile-steps (perfect balance).
// 4 waves; wave w owns rows [qt*128 + w*32, +32) (2 subtiles of 16).
// Swapped mfma(K,Q): lane (g=l>>4, q=l&15) holds S^T[kv = c*16+g*4+r][q].
__global__ __launch_bounds__(256, 2) void attn_kernel(
    const u16* __restrict__ Qb, const u16* __restrict__ Kb,
    const u16* __restrict__ VT, u16* __restrict__ Ob) {
  const int jj = blockIdx.x;  // 0..7
  const int h = blockIdx.y, b = blockIdx.z;
  const int kvh = h >> 2;
  const int t = threadIdx.x;
  const int lane = t & 63;
  const int w = t >> 6;
  const int q15 = lane & 15, g = lane >> 4;

  __shared__ __align__(16) u16 Ks[2][64 * 64];
  __shared__ __align__(16) u16 Vs[2][64 * 64];  // V^T tile: [d][kv]
  __shared__ __align__(16) u32 Pu[4][16 * 32];  // per-wave P / epilogue buffer

  const size_t Krow0 = (size_t)b * 2048;
  const size_t Vrow0 = ((size_t)b * 8 + kvh) * 64;

  auto stage = [&](int buf, int kvbase) {
#pragma unroll
    for (int c = 0; c < 2; ++c) {
      int chunk = c * 256 + t;
      int row = chunk >> 3, gg = chunk & 7;
      int gcs = (gg ^ (row & 7)) * 8;
      gload_lds16(&Kb[(Krow0 + kvbase + row) * 512 + kvh * 64 + gcs],
                  &Ks[buf][chunk * 8]);
      gload_lds16(&VT[(Vrow0 + row) * 2048 + kvbase + gcs],
                  &Vs[buf][chunk * 8]);
    }
  };

  const int swzB = (q15 & 7) << 3;  // u16-unit frag-read swizzle (matches stage)
  const int swzP = (q15 & 7) << 2;  // u32-unit swizzle for Pu
  u32* const pw = &Pu[w][0];
  const int nA = 2 * (15 - jj) + 2;  // phase-A kv-steps
  const int nsteps = 34;

  stage(0, 0);
  __syncthreads();
  int cur = 0;
  int ss = 0;

#pragma unroll
  for (int ph = 0; ph < 2; ++ph) {
    const int qt = ph ? jj : 15 - jj;
    const int nkv = 2 * qt + 2;
    const int wq0 = qt * 128 + w * 32;
    const int mylast = (wq0 + 31) >> 6;

    // Q fragments: qf[sub][ks] — B-operand layout (row=q15, k-chunk=g*8)
    bf16x8 qf[2][2];
    {
      const u16* q0 = &Qb[((size_t)b * 2048 + wq0 + q15) * 2048 + h * 64 + g * 8];
      qf[0][0] = *reinterpret_cast<const bf16x8*>(q0);
      qf[0][1] = *reinterpret_cast<const bf16x8*>(q0 + 32);
      qf[1][0] = *reinterpret_cast<const bf16x8*>(q0 + 16 * 2048);
      qf[1][1] = *reinterpret_cast<const bf16x8*>(q0 + 16 * 2048 + 32);
    }

    f32x4 oo[2][4];  // O^T accum: oo[sub][c2], d = c2*16+g*4+r, col q=q15
#pragma unroll
    for (int s2 = 0; s2 < 2; s2++)
#pragma unroll
      for (int c = 0; c < 4; c++)
#pragma unroll
        for (int r = 0; r < 4; r++) oo[s2][c][r] = 0.f;
    float mr[2] = {-1e30f, -1e30f}, lr[2] = {0.f, 0.f};

    for (int kv = 0; kv < nkv; ++kv, ++ss) {
      const int kvbase = kv << 6;
      if (ss + 1 < nsteps) {
        int nb = (ss + 1 < nA) ? (ss + 1) : (ss + 1 - nA);
        stage(cur ^ 1, nb << 6);
      }

      if (kv <= mylast) {
        // ---- S^T = K Q^T : D[kv][q] ----
        f32x4 s[2][4];
#pragma unroll
        for (int s2 = 0; s2 < 2; s2++)
#pragma unroll
          for (int c = 0; c < 4; c++)
#pragma unroll
            for (int r = 0; r < 4; r++) s[s2][c][r] = 0.f;
        __builtin_amdgcn_s_setprio(1);
#pragma unroll
        for (int ks = 0; ks < 2; ++ks) {
          const int kcol = (ks * 32 + g * 8) ^ swzB;
#pragma unroll
          for (int c = 0; c < 4; c++) {
            bf16x8 kb = *reinterpret_cast<const bf16x8*>(
                &Ks[cur][(c * 16 + q15) * 64 + kcol]);
            s[0][c] = __builtin_amdgcn_mfma_f32_16x16x32_bf16(kb, qf[0][ks], s[0][c], 0, 0, 0);
            s[1][c] = __builtin_amdgcn_mfma_f32_16x16x32_bf16(kb, qf[1][ks], s[1][c], 0, 0, 0);
          }
        }
        __builtin_amdgcn_s_setprio(0);

        bf16x8 pb[2][2];
#pragma unroll
        for (int sub = 0; sub < 2; ++sub) {
          const int qg = wq0 + sub * 16 + q15;
          // causal mask (diagonal tiles only; wave-uniform branch)
          if (kvbase + 63 > wq0 + sub * 16) {
#pragma unroll
            for (int c = 0; c < 4; c++)
#pragma unroll
              for (int r = 0; r < 4; r++)
                if (kvbase + c * 16 + g * 4 + r > qg) s[sub][c][r] = -1e30f;
          }
          // in-lane max over 16, then cross-g reduce (2 shfl)
          float mx0 = fmaxf(fmaxf(s[sub][0][0], s[sub][0][1]), fmaxf(s[sub][0][2], s[sub][0][3]));
          float mx1 = fmaxf(fmaxf(s[sub][1][0], s[sub][1][1]), fmaxf(s[sub][1][2], s[sub][1][3]));
          float mx2 = fmaxf(fmaxf(s[sub][2][0], s[sub][2][1]), fmaxf(s[sub][2][2], s[sub][2][3]));
          float mx3 = fmaxf(fmaxf(s[sub][3][0], s[sub][3][1]), fmaxf(s[sub][3][2], s[sub][3][3]));
          float mx = fmaxf(fmaxf(mx0, mx1), fmaxf(mx2, mx3));
          mx = fmaxf(mx, __shfl_xor(mx, 16));
          mx = fmaxf(mx, __shfl_xor(mx, 32));
          // defer-max (T13): only rescale when tile max meaningfully exceeds mr
          if (!__all(mx <= mr[sub] + 8.f)) {
            float mnew = fmaxf(mr[sub], mx);
            float alpha = fexp2(mr[sub] - mnew);
            lr[sub] *= alpha;
#pragma unroll
            for (int c = 0; c < 4; c++)
#pragma unroll
              for (int r = 0; r < 4; r++) oo[sub][c][r] *= alpha;
            mr[sub] = mnew;
          }
          float p[4][4];
          float rs = 0.f;
#pragma unroll
          for (int c = 0; c < 4; c++) {
            float t0 = fexp2(s[sub][c][0] - mr[sub]);
            float t1 = fexp2(s[sub][c][1] - mr[sub]);
            float t2 = fexp2(s[sub][c][2] - mr[sub]);
            float t3 = fexp2(s[sub][c][3] - mr[sub]);
            p[c][0] = t0; p[c][1] = t1; p[c][2] = t2; p[c][3] = t3;
            rs += (t0 + t1) + (t2 + t3);
          }
          rs += __shfl_xor(rs, 16);
          rs += __shfl_xor(rs, 32);
          lr[sub] += rs;
          // pack P -> per-wave LDS (b64 writes, K-style swizzle)
#pragma unroll
          for (int c = 0; c < 4; c++) {
            u64 wv = (u64)packbf2(p[c][0], p[c][1]) |
                     ((u64)packbf2(p[c][2], p[c][3]) << 32);
            *reinterpret_cast<u64*>(&pw[q15 * 32 + ((c * 8 + g * 2) ^ swzP)]) = wv;
          }
          // read back as B-fragment (row=q15, kv-chunk=g*8)
#pragma unroll
          for (int ks = 0; ks < 2; ++ks)
            pb[sub][ks] = *reinterpret_cast<const bf16x8*>(
                &pw[q15 * 32 + ((ks * 16 + g * 4) ^ swzP)]);
        }

        // ---- O^T += V^T P : D[d][q] ----
        __builtin_amdgcn_s_setprio(1);
#pragma unroll
        for (int ks = 0; ks < 2; ++ks) {
          const int vcol = (ks * 32 + g * 8) ^ swzB;
#pragma unroll
          for (int c2 = 0; c2 < 4; c2++) {
            bf16x8 vb = *reinterpret_cast<const bf16x8*>(
                &Vs[cur][(c2 * 16 + q15) * 64 + vcol]);
            oo[0][c2] = __builtin_amdgcn_mfma_f32_16x16x32_bf16(vb, pb[0][ks], oo[0][c2], 0, 0, 0);
            oo[1][c2] = __builtin_amdgcn_mfma_f32_16x16x32_bf16(vb, pb[1][ks], oo[1][c2], 0, 0, 0);
          }
        }
        __builtin_amdgcn_s_setprio(0);
      }

      __syncthreads();
      cur ^= 1;
    }

    // ---- epilogue: normalize, transpose via per-wave LDS, coalesced store ----
    const int qq = lane >> 2, cl = lane & 3;
    const int swq = (qq & 7) << 2;
#pragma unroll
    for (int sub = 0; sub < 2; ++sub) {
      float rcp = 1.0f / lr[sub];
#pragma unroll
      for (int c2 = 0; c2 < 4; c2++) {
        u64 wv = (u64)packbf2(oo[sub][c2][0] * rcp, oo[sub][c2][1] * rcp) |
                 ((u64)packbf2(oo[sub][c2][2] * rcp, oo[sub][c2][3] * rcp) << 32);
        *reinterpret_cast<u64*>(&pw[q15 * 32 + ((c2 * 8 + g * 2) ^ swzP)]) = wv;
      }
      uint4 d0 = *reinterpret_cast<const uint4*>(&pw[qq * 32 + ((cl * 4) ^ swq)]);
      uint4 d1 = *reinterpret_cast<const uint4*>(&pw[qq * 32 + ((cl * 4 + 16) ^ swq)]);
      u32* og = (u32*)Ob + ((size_t)b * 2048 + wq0 + sub * 16 + qq) * 1024 + h * 32;
      *reinterpret_cast<uint4*>(&og[cl * 4]) = d0;
      *reinterpret_cast<uint4*>(&og[cl * 4 + 16]) = d1;
    }
  }
}

// ---------------- launcher ----------------
extern "C" void kernel_launch(void* const* d_in, const int* in_sizes, int n_in,
                              void* d_out, int out_size, void* d_ws, size_t ws_size,
                              hipStream_t stream) {
  const float* x = (const float*)d_in[0];
  const float* wq = (const float*)d_in[1];
  const float* wk = (const float*)d_in[2];
  const float* wv = (const float*)d_in[3];
  const float* wo = (const float*)d_in[4];
  float* out = (float*)d_out;

  char* p = (char*)d_ws;
  u16* xb = (u16*)p;   p += (size_t)4096 * 2048 * 2;
  u16* wqT = (u16*)p;  p += (size_t)2048 * 2048 * 2;  // wqT|wkT|wvT contiguous:
  u16* wkT = (u16*)p;  p += (size_t)512 * 2048 * 2;   //   fused QKV GEMM reads
  u16* wvT = (u16*)p;  p += (size_t)512 * 2048 * 2;   //   them as one 3072x2048 BT
  u16* woT = (u16*)p;  p += (size_t)2048 * 2048 * 2;
  u16* Qb = (u16*)p;   p += (size_t)4096 * 2048 * 2;
  u16* Kb = (u16*)p;   p += (size_t)4096 * 512 * 2;
  u16* Vb = (u16*)p;   p += (size_t)4096 * 512 * 2;
  u16* VTb = (u16*)p;  p += (size_t)2 * 512 * 2048 * 2;
  u16* attn = xb;  // reuse: x_bf16 dead after projections

  cast_f32_bf16<<<8192, 256, 0, stream>>>(x, xb, 4096 * 2048);
  transpose_cast<<<dim3(2048 / 32, 2048 / 32), 256, 0, stream>>>(wq, wqT, 2048, 2048);
  transpose_cast<<<dim3(512 / 32, 2048 / 32), 256, 0, stream>>>(wk, wkT, 2048, 512);
  transpose_cast<<<dim3(512 / 32, 2048 / 32), 256, 0, stream>>>(wv, wvT, 2048, 512);
  transpose_cast<<<dim3(2048 / 32, 2048 / 32), 256, 0, stream>>>(wo, woT, 2048, 2048);

  // fused Q|K|V projection (Q pre-scaled by QSCALE inside epilogue)
  gemm_bt<3><<<dim3(3072 / 128, 4096 / 128), 256, 0, stream>>>(
      xb, wqT, nullptr, Qb, Kb, Vb, 4096, 3072, 2048);

  transpose_u16<<<dim3(2048 / 32, 512 / 32, 2), 256, 0, stream>>>(Vb, VTb);

  attn_kernel<<<dim3(8, 32, 2), 256, 0, stream>>>(Qb, Kb, VTb, attn);

  gemm_bt<1><<<dim3(2048 / 128, 4096 / 128), 256, 0, stream>>>(
      attn, woT, out, nullptr, nullptr, nullptr, 4096, 2048, 2048);
}